// Round 2
// baseline (2303.916 us; speedup 1.0000x reference)
//
#include <hip/hip_runtime.h>
#include <math.h>

// ---------------------------------------------------------------------------
// ResidualVQ forward: 6x(conv3x3 s2 + BN + ReLU) -> GRU(32 steps) -> 3x VQ
// All fp32. L0 activation is never materialized (stats pass + recompute in L1).
// ---------------------------------------------------------------------------

__global__ void transpose_kernel(const float* __restrict__ in, float* __restrict__ out,
                                 int R, int C) {
  int n = R * C;
  for (int t = blockIdx.x * blockDim.x + threadIdx.x; t < n; t += gridDim.x * blockDim.x) {
    int i = t / C, j = t % C;
    out[j * R + i] = in[t];
  }
}

__global__ __launch_bounds__(256) void se_kernel(const float* __restrict__ ET,
                                                 float* __restrict__ sE) {
  int c = blockIdx.x * 256 + threadIdx.x;  // 0..1023
  float s = 0.f;
  for (int k = 0; k < 256; ++k) {
    float v = ET[k * 1024 + c];
    s = fmaf(v, v, s);
  }
  sE[c] = s;
}

// conv3x3 stride2 pad1; prev-layer BN affine+relu folded into load.
// STORE=false: stats-only (y unused).
template <int CI, int COG, int WO, int ROWS, int WI, int HI, int HO, bool AFF, bool STORE>
__global__ __launch_bounds__(WO * ROWS) void conv_bn_kernel(
    const float* __restrict__ x, const float* __restrict__ w,
    const float* __restrict__ aff, float* __restrict__ y,
    float* __restrict__ part, int CO, int TILES) {
  constexpr int TW = WI + 2;
  constexpr int TH = 2 * ROWS + 1;
  constexpr int NTH = WO * ROWS;
  __shared__ float tile[TH * TW];
  __shared__ float red[NTH];

  const int tid = threadIdx.x;
  const int fo = tid % WO;
  const int tr = tid / WO;
  const int to0 = blockIdx.x * ROWS;
  const int to = to0 + tr;
  const int co0 = blockIdx.y * COG;
  const int b = blockIdx.z;

  float acc[COG];
#pragma unroll
  for (int c = 0; c < COG; ++c) acc[c] = 0.f;

  const float* xb = x + (size_t)b * CI * HI * WI;

  for (int ci = 0; ci < CI; ++ci) {
    float sc = 0.f, sh = 0.f;
    if (AFF) { sc = aff[ci]; sh = aff[CI + ci]; }
    const float* xc = xb + (size_t)ci * HI * WI;
    for (int i = tid; i < TH * TW; i += NTH) {
      int r = i / TW, c2 = i % TW;
      int gih = 2 * to0 - 1 + r;
      int giw = c2 - 1;
      float v = 0.f;
      if (gih >= 0 && gih < HI && giw >= 0 && giw < WI) {
        v = xc[gih * WI + giw];
        if (AFF) v = fmaxf(fmaf(v, sc, sh), 0.f);
      }
      tile[i] = v;
    }
    __syncthreads();

    float xv[9];
    int base = (2 * tr) * TW + 2 * fo;
#pragma unroll
    for (int kh = 0; kh < 3; ++kh)
#pragma unroll
      for (int kw = 0; kw < 3; ++kw)
        xv[kh * 3 + kw] = tile[base + kh * TW + kw];

    const float* wp = w + ((size_t)co0 * CI + ci) * 9;
#pragma unroll
    for (int c = 0; c < COG; ++c) {
      const float* wc = wp + (size_t)c * CI * 9;
#pragma unroll
      for (int q = 0; q < 9; ++q) acc[c] = fmaf(xv[q], wc[q], acc[c]);
    }
    __syncthreads();
  }

  const bool valid = (to < HO);
  const int P = (int)gridDim.z * TILES;
  const int pidx = b * TILES + blockIdx.x;
#pragma unroll
  for (int c = 0; c < COG; ++c) {
    float v = valid ? acc[c] : 0.f;
    if (STORE && valid) y[(((size_t)b * CO + co0 + c) * HO + to) * WO + fo] = v;
    red[tid] = v;
    __syncthreads();
    for (int s = 128; s > 0; s >>= 1) {
      if (tid < s && tid + s < NTH) red[tid] += red[tid + s];
      __syncthreads();
    }
    if (tid == 0) part[(size_t)(co0 + c) * P + pidx] = red[0];
    __syncthreads();
    red[tid] = v * v;
    __syncthreads();
    for (int s = 128; s > 0; s >>= 1) {
      if (tid < s && tid + s < NTH) red[tid] += red[tid + s];
      __syncthreads();
    }
    if (tid == 0) part[(size_t)(CO + co0 + c) * P + pidx] = red[0];
    __syncthreads();
  }
}

// Fused L1: recompute normalized L0 tile from speech (CI of L0 is 1),
// then conv1 3x3 s2 over it. Output raw L1 [64][32][500][20] + stats.
__global__ __launch_bounds__(240) void conv1_fused_kernel(
    const float* __restrict__ speech,  // [64][2000][80]
    const float* __restrict__ w0,      // [32][1][3][3]
    const float* __restrict__ aff0,    // scale[32] | shift[32]
    const float* __restrict__ w1,      // [32][32][3][3]
    float* __restrict__ y,             // [64][32][500][20]
    float* __restrict__ part, int TILES) {
  constexpr int ROWS = 12, WO = 20, NTH = 240;
  __shared__ float sp[51 * 80];   // speech tile
  __shared__ float l0t[25 * 42];  // one L0 channel, normalized+relu, padded
  __shared__ float w0s[288];
  __shared__ float red[NTH];

  const int tid = threadIdx.x;
  const int fo = tid % WO;
  const int tr = tid / WO;
  const int to0 = blockIdx.x * ROWS;
  const int to = to0 + tr;
  const int co0 = blockIdx.y * 8;
  const int b = blockIdx.z;

  const float* sb = speech + (size_t)b * 2000 * 80;
  const int sr0 = 4 * to0 - 3;
  for (int i = tid; i < 51 * 80; i += NTH) {
    int r = i / 80, c = i % 80;
    int gr = sr0 + r;
    sp[i] = (gr >= 0 && gr < 2000) ? sb[gr * 80 + c] : 0.f;
  }
  for (int i = tid; i < 288; i += NTH) w0s[i] = w0[i];

  float acc[8];
#pragma unroll
  for (int c = 0; c < 8; ++c) acc[c] = 0.f;
  __syncthreads();

  const int l0r0 = 2 * to0 - 1;
  for (int ci = 0; ci < 32; ++ci) {
    float sc = aff0[ci], sh = aff0[32 + ci];
    const float* wk = w0s + ci * 9;
    for (int i = tid; i < 25 * 42; i += NTH) {
      int r = i / 42, c2 = i % 42;
      int h0 = l0r0 + r;
      int wcol = c2 - 1;
      float v = 0.f;
      if (h0 >= 0 && h0 < 1000 && wcol >= 0 && wcol < 40) {
        int spr = 2 * r;        // speech tile top row of the 3x3 patch
        int spc = 2 * wcol - 1; // speech col of patch start (-1..77)
        float a = 0.f;
#pragma unroll
        for (int kh = 0; kh < 3; ++kh) {
          const float* row = sp + (spr + kh) * 80;
#pragma unroll
          for (int kw = 0; kw < 3; ++kw) {
            int cc = spc + kw;
            float s = (cc >= 0 && cc < 80) ? row[cc] : 0.f;
            a = fmaf(s, wk[kh * 3 + kw], a);
          }
        }
        v = fmaxf(fmaf(a, sc, sh), 0.f);
      }
      l0t[i] = v;
    }
    __syncthreads();

    float xv[9];
    int base = (2 * tr) * 42 + 2 * fo;
#pragma unroll
    for (int kh = 0; kh < 3; ++kh)
#pragma unroll
      for (int kw = 0; kw < 3; ++kw)
        xv[kh * 3 + kw] = l0t[base + kh * 42 + kw];

    const float* wp = w1 + ((size_t)co0 * 32 + ci) * 9;
#pragma unroll
    for (int c = 0; c < 8; ++c) {
      const float* wc = wp + (size_t)c * 32 * 9;
#pragma unroll
      for (int q = 0; q < 9; ++q) acc[c] = fmaf(xv[q], wc[q], acc[c]);
    }
    __syncthreads();
  }

  const bool valid = (to < 500);
  const int P = 64 * TILES;
  const int pidx = b * TILES + blockIdx.x;
#pragma unroll
  for (int c = 0; c < 8; ++c) {
    float v = valid ? acc[c] : 0.f;
    if (valid) y[(((size_t)b * 32 + co0 + c) * 500 + to) * 20 + fo] = v;
    red[tid] = v;
    __syncthreads();
    for (int s = 128; s > 0; s >>= 1) {
      if (tid < s && tid + s < NTH) red[tid] += red[tid + s];
      __syncthreads();
    }
    if (tid == 0) part[(size_t)(co0 + c) * P + pidx] = red[0];
    __syncthreads();
    red[tid] = v * v;
    __syncthreads();
    for (int s = 128; s > 0; s >>= 1) {
      if (tid < s && tid + s < NTH) red[tid] += red[tid + s];
      __syncthreads();
    }
    if (tid == 0) part[(size_t)(32 + co0 + c) * P + pidx] = red[0];
    __syncthreads();
  }
}

__global__ __launch_bounds__(256) void bn_finalize(
    const float* __restrict__ part, const float* __restrict__ g,
    const float* __restrict__ bb, float* __restrict__ aff, int CO, int P,
    double invN) {
  __shared__ double s1[256];
  __shared__ double s2[256];
  int c = blockIdx.x, tid = threadIdx.x;
  double a = 0, q = 0;
  for (int i = tid; i < P; i += 256) {
    a += (double)part[(size_t)c * P + i];
    q += (double)part[(size_t)(CO + c) * P + i];
  }
  s1[tid] = a;
  s2[tid] = q;
  __syncthreads();
  for (int s = 128; s > 0; s >>= 1) {
    if (tid < s) { s1[tid] += s1[tid + s]; s2[tid] += s2[tid + s]; }
    __syncthreads();
  }
  if (tid == 0) {
    double mean = s1[0] * invN;
    double var = s2[0] * invN - mean * mean;
    float scale = g[c] * (float)(1.0 / sqrt(var + 1e-5));
    aff[c] = scale;
    aff[CO + c] = bb[c] - (float)mean * scale;
  }
}

__global__ __launch_bounds__(256) void hs_kernel(const float* __restrict__ raw,
                                                 const float* __restrict__ aff5,
                                                 float* __restrict__ hs) {
  int i = blockIdx.x * 256 + threadIdx.x;  // < 524288
  if (i >= 524288) return;
  int b = i >> 13;
  int j = i & 8191;
  int t = j >> 8;
  int d = j & 255;
  int c = d >> 1;
  int f = d & 1;
  float sc = aff5[c], sh = aff5[128 + c];
  float v = raw[(((size_t)b * 128 + c) * 32 + t) * 2 + f];
  hs[i] = fmaxf(fmaf(v, sc, sh), 0.f);
}

__global__ __launch_bounds__(256) void xw_kernel(const float* __restrict__ hs,
                                                 const float* __restrict__ w_ihT,
                                                 const float* __restrict__ bih,
                                                 float* __restrict__ xw) {
  __shared__ float sh[8 * 256];
  int tid = threadIdx.x;
  int bt0 = blockIdx.x * 8;
  for (int i = tid; i < 8 * 256; i += 256) sh[i] = hs[(size_t)bt0 * 256 + i];
  __syncthreads();
  float acc[3][8];
#pragma unroll
  for (int g = 0; g < 3; ++g)
#pragma unroll
    for (int r = 0; r < 8; ++r) acc[g][r] = 0.f;
  for (int k = 0; k < 256; ++k) {
    float w0 = w_ihT[k * 768 + tid];
    float w1 = w_ihT[k * 768 + 256 + tid];
    float w2 = w_ihT[k * 768 + 512 + tid];
#pragma unroll
    for (int r = 0; r < 8; ++r) {
      float hv = sh[r * 256 + k];
      acc[0][r] = fmaf(hv, w0, acc[0][r]);
      acc[1][r] = fmaf(hv, w1, acc[1][r]);
      acc[2][r] = fmaf(hv, w2, acc[2][r]);
    }
  }
  float b0 = bih[tid], b1 = bih[256 + tid], b2 = bih[512 + tid];
  for (int r = 0; r < 8; ++r) {
    size_t base = (size_t)(bt0 + r) * 768;
    xw[base + tid] = acc[0][r] + b0;
    xw[base + 256 + tid] = acc[1][r] + b1;
    xw[base + 512 + tid] = acc[2][r] + b2;
  }
}

__global__ __launch_bounds__(768) void gru_kernel(const float* __restrict__ xw,
                                                  const float* __restrict__ w_hhT,
                                                  const float* __restrict__ bhh,
                                                  float* __restrict__ zout) {
  __shared__ float h[256];
  __shared__ float gh[768];
  int b = blockIdx.x, j = threadIdx.x;
  if (j < 256) h[j] = 0.f;
  __syncthreads();
  float bh = bhh[j];
  for (int t = 0; t < 32; ++t) {
    float acc = 0.f;
#pragma unroll 8
    for (int k = 0; k < 256; ++k) acc = fmaf(h[k], w_hhT[k * 768 + j], acc);
    gh[j] = acc + bh;
    __syncthreads();
    float hnew = 0.f;
    if (j < 256) {
      const float* xt = xw + ((size_t)b * 32 + t) * 768;
      float ir = xt[j], iz = xt[256 + j], inn = xt[512 + j];
      float r = 1.f / (1.f + expf(-(ir + gh[j])));
      float zz = 1.f / (1.f + expf(-(iz + gh[256 + j])));
      float n = tanhf(fmaf(r, gh[512 + j], inn));
      hnew = (1.f - zz) * n + zz * h[j];
    }
    __syncthreads();
    if (j < 256) h[j] = hnew;
    __syncthreads();
  }
  if (j < 256) zout[(size_t)b * 256 + j] = h[j];
}

template <int FIRST, int LAST>
__global__ __launch_bounds__(256) void vq_stage(
    const float* __restrict__ rin, const float* __restrict__ ET,
    const float* __restrict__ sE, const float* __restrict__ E,
    float* __restrict__ zq1, float* __restrict__ zq2, float* __restrict__ rout,
    float* __restrict__ msep, float* __restrict__ i1out,
    const float* __restrict__ z0, float* __restrict__ zqsum) {
  __shared__ float rz[256];
  __shared__ float rs[256];
  __shared__ int ri[256];
  __shared__ int bidx;
  int b = blockIdx.x, tid = threadIdx.x;
  rz[tid] = rin[(size_t)b * 256 + tid];
  __syncthreads();
  float a0 = 0.f, a1 = 0.f, a2 = 0.f, a3 = 0.f;
  for (int k = 0; k < 256; ++k) {
    float zk = rz[k];
    const float* row = ET + (size_t)k * 1024 + tid;
    a0 = fmaf(zk, row[0], a0);
    a1 = fmaf(zk, row[256], a1);
    a2 = fmaf(zk, row[512], a2);
    a3 = fmaf(zk, row[768], a3);
  }
  float s0 = sE[tid] - 2.f * a0;
  float s1 = sE[256 + tid] - 2.f * a1;
  float s2 = sE[512 + tid] - 2.f * a2;
  float s3 = sE[768 + tid] - 2.f * a3;
  float bs = s0;
  int bi = tid;
  if (s1 < bs) { bs = s1; bi = 256 + tid; }
  if (s2 < bs) { bs = s2; bi = 512 + tid; }
  if (s3 < bs) { bs = s3; bi = 768 + tid; }
  rs[tid] = bs;
  ri[tid] = bi;
  __syncthreads();
  for (int s = 128; s > 0; s >>= 1) {
    if (tid < s) {
      float os = rs[tid + s];
      int oi = ri[tid + s];
      if (os < rs[tid] || (os == rs[tid] && oi < ri[tid])) { rs[tid] = os; ri[tid] = oi; }
    }
    __syncthreads();
  }
  if (tid == 0) {
    bidx = ri[0];
    if (FIRST) i1out[b] = (float)ri[0];
  }
  __syncthreads();
  int idx = bidx;
  float zq = E[(size_t)idx * 256 + tid];
  float rv = rz[tid];
  float d = zq - rv;
  float rn = rv - zq;
  zq1[(size_t)b * 768 + tid] = zq;
  zq2[(size_t)b * 256 + tid] = zq;
  rout[(size_t)b * 256 + tid] = rn;
  if (LAST) zqsum[(size_t)b * 256 + tid] = z0[(size_t)b * 256 + tid] - rn;
  rs[tid] = d * d;
  __syncthreads();
  for (int s = 128; s > 0; s >>= 1) {
    if (tid < s) rs[tid] += rs[tid + s];
    __syncthreads();
  }
  if (tid == 0) msep[b] = rs[0];
}

__global__ void loss_kernel(const float* __restrict__ msep, float* __restrict__ out) {
  if (threadIdx.x == 0 && blockIdx.x == 0) {
    float s = 0.f;
    for (int i = 0; i < 192; ++i) s += msep[i];
    out[0] = 1.25f * s / 16384.0f;
  }
}

extern "C" void kernel_launch(void* const* d_in, const int* in_sizes, int n_in,
                              void* d_out, int out_size, void* d_ws, size_t ws_size,
                              hipStream_t stream) {
  const float* speech = (const float*)d_in[0];
  const float* cw[6];
  const float* gg[6];
  const float* bbp[6];
  for (int i = 0; i < 6; ++i) {
    cw[i] = (const float*)d_in[1 + 3 * i];
    gg[i] = (const float*)d_in[2 + 3 * i];
    bbp[i] = (const float*)d_in[3 + 3 * i];
  }
  const float* w_ih = (const float*)d_in[19];
  const float* w_hh = (const float*)d_in[20];
  const float* bih = (const float*)d_in[21];
  const float* bhh = (const float*)d_in[22];
  const float* cb[3] = {(const float*)d_in[23], (const float*)d_in[24], (const float*)d_in[25]};
  float* out = (float*)d_out;
  float* ws_f = (float*)d_ws;
  (void)in_sizes; (void)n_in; (void)out_size;

  // workspace layout (floats) — total 37,310,752 floats = 149.2 MB
  size_t off = 0;
  float* act1 = ws_f + off; off += 20480000ull;  // L1 raw [64][32][500][20]
  float* act2 = ws_f + off; off += 10240000ull;  // L2 raw, later L4 raw
  float* act3 = ws_f + off; off += 2560000ull;   // L3 raw, later L5 raw
  float* part = ws_f + off; off += 700000ull;    // BN partials
  float* affs = ws_f + off; off += 1536ull;      // per-layer scale/shift (stride 256)
  float* w_ihT = ws_f + off; off += 196608ull;
  float* w_hhT = ws_f + off; off += 196608ull;
  float* hs = ws_f + off; off += 524288ull;
  float* xw = ws_f + off; off += 1572864ull;
  float* zb = ws_f + off; off += 16384ull;
  float* rA = ws_f + off; off += 16384ull;
  float* rB = ws_f + off; off += 16384ull;
  float* ET0 = ws_f + off; off += 262144ull;
  float* ET1 = ws_f + off; off += 262144ull;
  float* ET2 = ws_f + off; off += 262144ull;
  float* sEp = ws_f + off; off += 3072ull;
  float* msep = ws_f + off; off += 192ull;

  // If the workspace is too small, launch nothing (bench will show absmax
  // ~1000 instead of a GPU memory-fault core dump -> diagnostic).
  if (ws_size < off * sizeof(float)) return;

  const size_t OFF_LOSS = 49152;
  const size_t OFF_I1 = 49153;
  const size_t OFF_CB1 = 49217;
  const size_t OFF_CB2 = 65601;
  const size_t OFF_CB3 = 81985;
  const size_t OFF_CBSUM = 98369;

  transpose_kernel<<<256, 256, 0, stream>>>(w_ih, w_ihT, 768, 256);
  transpose_kernel<<<256, 256, 0, stream>>>(w_hh, w_hhT, 768, 256);
  transpose_kernel<<<256, 256, 0, stream>>>(cb[0], ET0, 1024, 256);
  transpose_kernel<<<256, 256, 0, stream>>>(cb[1], ET1, 1024, 256);
  transpose_kernel<<<256, 256, 0, stream>>>(cb[2], ET2, 1024, 256);
  se_kernel<<<4, 256, 0, stream>>>(ET0, sEp);
  se_kernel<<<4, 256, 0, stream>>>(ET1, sEp + 1024);
  se_kernel<<<4, 256, 0, stream>>>(ET2, sEp + 2048);

  // L0: stats only (no store)
  conv_bn_kernel<1, 8, 40, 6, 80, 2000, 1000, false, false>
      <<<dim3(167, 4, 64), 240, 0, stream>>>(speech, cw[0], nullptr, nullptr, part, 32, 167);
  bn_finalize<<<32, 256, 0, stream>>>(part, gg[0], bbp[0], affs + 0, 32, 64 * 167,
                                      1.0 / (64.0 * 1000 * 40));
  // L1: fused (recomputes normalized L0 from speech)
  conv1_fused_kernel<<<dim3(42, 4, 64), 240, 0, stream>>>(speech, cw[0], affs + 0,
                                                          cw[1], act1, part, 42);
  bn_finalize<<<32, 256, 0, stream>>>(part, gg[1], bbp[1], affs + 256, 32, 64 * 42,
                                      1.0 / (64.0 * 500 * 20));
  // L2
  conv_bn_kernel<32, 8, 10, 24, 20, 500, 250, true, true>
      <<<dim3(11, 8, 64), 240, 0, stream>>>(act1, cw[2], affs + 256, act2, part, 64, 11);
  bn_finalize<<<64, 256, 0, stream>>>(part, gg[2], bbp[2], affs + 512, 64, 64 * 11,
                                      1.0 / (64.0 * 250 * 10));
  // L3
  conv_bn_kernel<64, 8, 5, 48, 10, 250, 125, true, true>
      <<<dim3(3, 8, 64), 240, 0, stream>>>(act2, cw[3], affs + 512, act3, part, 64, 3);
  bn_finalize<<<64, 256, 0, stream>>>(part, gg[3], bbp[3], affs + 768, 64, 64 * 3,
                                      1.0 / (64.0 * 125 * 5));
  // L4 (reads act3, writes act2 — L2 raw is dead)
  conv_bn_kernel<64, 8, 3, 63, 5, 125, 63, true, true>
      <<<dim3(1, 16, 64), 189, 0, stream>>>(act3, cw[4], affs + 768, act2, part, 128, 1);
  bn_finalize<<<128, 256, 0, stream>>>(part, gg[4], bbp[4], affs + 1024, 128, 64,
                                       1.0 / (64.0 * 63 * 3));
  // L5 (reads act2, writes act3 — L3 raw is dead)
  conv_bn_kernel<128, 8, 2, 32, 3, 63, 32, true, true>
      <<<dim3(1, 16, 64), 64, 0, stream>>>(act2, cw[5], affs + 1024, act3, part, 128, 1);
  bn_finalize<<<128, 256, 0, stream>>>(part, gg[5], bbp[5], affs + 1280, 128, 64,
                                       1.0 / (64.0 * 32 * 2));

  hs_kernel<<<2048, 256, 0, stream>>>(act3, affs + 1280, hs);
  xw_kernel<<<256, 256, 0, stream>>>(hs, w_ihT, bih, xw);
  gru_kernel<<<64, 768, 0, stream>>>(xw, w_hhT, bhh, zb);

  vq_stage<1, 0><<<64, 256, 0, stream>>>(zb, ET0, sEp, cb[0], out + 0, out + OFF_CB1,
                                         rA, msep + 0, out + OFF_I1, nullptr, nullptr);
  vq_stage<0, 0><<<64, 256, 0, stream>>>(rA, ET1, sEp + 1024, cb[1], out + 256,
                                         out + OFF_CB2, rB, msep + 64, nullptr, nullptr,
                                         nullptr);
  vq_stage<0, 1><<<64, 256, 0, stream>>>(rB, ET2, sEp + 2048, cb[2], out + 512,
                                         out + OFF_CB3, rA, msep + 128, nullptr, zb,
                                         out + OFF_CBSUM);
  loss_kernel<<<1, 64, 0, stream>>>(msep, out + OFF_LOSS);
}

// Round 3
// 1233.338 us; speedup vs baseline: 1.8680x; 1.8680x over previous
//
#include <hip/hip_runtime.h>
#include <math.h>

// ---------------------------------------------------------------------------
// ResidualVQ forward: 6x(conv3x3 s2 + BN + ReLU) -> GRU(32 steps) -> 3x VQ
// All fp32. L0 never materialized (stats pass + recompute inside L1).
// BN stats for stored layers via separate read-back kernel (BW-bound).
// ---------------------------------------------------------------------------

__global__ void transpose_kernel(const float* __restrict__ in, float* __restrict__ out,
                                 int R, int C) {
  int n = R * C;
  for (int t = blockIdx.x * blockDim.x + threadIdx.x; t < n; t += gridDim.x * blockDim.x) {
    int i = t / C, j = t % C;
    out[j * R + i] = in[t];
  }
}

__global__ __launch_bounds__(256) void se_kernel(const float* __restrict__ ET,
                                                 float* __restrict__ sE) {
  int c = blockIdx.x * 256 + threadIdx.x;  // 0..1023
  float s = 0.f;
  for (int k = 0; k < 256; ++k) {
    float v = ET[k * 1024 + c];
    s = fmaf(v, v, s);
  }
  sE[c] = s;
}

// -------------------- L0 stats (conv output never stored) ------------------
// grid (42, 1, 64), 256 threads. Each thread: 4 output rows (consecutive),
// 40-wide; 32 channels; wave-shuffle reduction (no syncthreads in epilogue).
__global__ __launch_bounds__(256) void conv0_stats_kernel(
    const float* __restrict__ speech, const float* __restrict__ w0,
    float* __restrict__ part) {
  constexpr int TS = 81, TH = 49, TN = TH * TS;
  __shared__ float sp[TN];
  const int tid = threadIdx.x;
  const int bx = blockIdx.x;
  const int b = blockIdx.z;
  const int to0 = bx * 24;
  const int sr0 = 2 * to0 - 1;
  const float* sb = speech + (size_t)b * 2000 * 80;
  for (int i = tid; i < TN; i += 256) {
    int r = i / TS, c = i % TS;
    int gr = sr0 + r, gc = c - 1;
    sp[i] = (gr >= 0 && gr < 2000 && gc >= 0 && gc < 80) ? sb[gr * 80 + gc] : 0.f;
  }
  __syncthreads();

  const int fo = tid % 40;
  const int trr = tid / 40;  // 0..6 (6 -> idle)
  const bool rowok = (trr < 6);
  const int r0 = rowok ? trr * 4 : 0;

  float xv4[4][9];
  {
    int sb0 = (2 * r0) * TS + 2 * fo;
    float p0 = sp[sb0], p1 = sp[sb0 + 1], p2 = sp[sb0 + 2];
#pragma unroll
    for (int k = 0; k < 4; ++k) {
      int mr = (2 * (r0 + k) + 1) * TS + 2 * fo;
      xv4[k][0] = p0; xv4[k][1] = p1; xv4[k][2] = p2;
      xv4[k][3] = sp[mr]; xv4[k][4] = sp[mr + 1]; xv4[k][5] = sp[mr + 2];
      xv4[k][6] = sp[mr + TS]; xv4[k][7] = sp[mr + TS + 1]; xv4[k][8] = sp[mr + TS + 2];
      p0 = xv4[k][6]; p1 = xv4[k][7]; p2 = xv4[k][8];
    }
  }
  bool val[4];
#pragma unroll
  for (int k = 0; k < 4; ++k) val[k] = rowok && (to0 + r0 + k < 1000);

  float s[32], q[32];
#pragma unroll
  for (int c = 0; c < 32; ++c) { s[c] = 0.f; q[c] = 0.f; }
#pragma unroll
  for (int c = 0; c < 32; ++c) {
    const float* wk = w0 + c * 9;  // uniform -> scalar loads
    float w0v = wk[0], w1v = wk[1], w2v = wk[2], w3v = wk[3], w4v = wk[4];
    float w5v = wk[5], w6v = wk[6], w7v = wk[7], w8v = wk[8];
#pragma unroll
    for (int k = 0; k < 4; ++k) {
      float a = xv4[k][0] * w0v;
      a = fmaf(xv4[k][1], w1v, a); a = fmaf(xv4[k][2], w2v, a);
      a = fmaf(xv4[k][3], w3v, a); a = fmaf(xv4[k][4], w4v, a);
      a = fmaf(xv4[k][5], w5v, a); a = fmaf(xv4[k][6], w6v, a);
      a = fmaf(xv4[k][7], w7v, a); a = fmaf(xv4[k][8], w8v, a);
      if (val[k]) { s[c] += a; q[c] = fmaf(a, a, q[c]); }
    }
  }
  const int wid = tid >> 6;
  const int lane = tid & 63;
  const int pidx = ((b * 42 + bx) << 2) | wid;
#pragma unroll
  for (int c = 0; c < 32; ++c) {
    float ss = s[c], qq = q[c];
#pragma unroll
    for (int m = 32; m >= 1; m >>= 1) {
      ss += __shfl_xor(ss, m, 64);
      qq += __shfl_xor(qq, m, 64);
    }
    if (lane == 0) {
      part[(size_t)c * 10752 + pidx] = ss;
      part[(size_t)(32 + c) * 10752 + pidx] = qq;
    }
  }
}

// -------------------- L1 fused (recompute normalized L0) -------------------
// grid (42, 1, 64), 256 threads, all 32 output channels per block.
__global__ __launch_bounds__(256) void conv1_fused_kernel(
    const float* __restrict__ speech, const float* __restrict__ w0,
    const float* __restrict__ aff0, const float* __restrict__ w1,
    float* __restrict__ y) {
  constexpr int SPS = 81, SPH = 51, SPN = SPH * SPS;
  constexpr int LTS = 43, LTH = 25;
  __shared__ float sp[SPN];
  __shared__ float l0t[2][LTH * LTS];
  const int tid = threadIdx.x;
  const int bx = blockIdx.x;
  const int b = blockIdx.z;
  const int to0 = bx * 12;
  const int l0r0 = 2 * to0 - 1;
  const int sr0 = 4 * to0 - 3;
  const float* sb = speech + (size_t)b * 2000 * 80;
  for (int i = tid; i < SPN; i += 256) {
    int r = i / SPS, c = i % SPS;
    int gr = sr0 + r, gc = c - 1;
    sp[i] = (gr >= 0 && gr < 2000 && gc >= 0 && gc < 80) ? sb[gr * 80 + gc] : 0.f;
  }

  const int fc = tid % 42;
  const int fr0 = tid / 42;
  const bool filler = (tid < 210);
  const int wcol = fc - 1;
  const bool colok = (wcol >= 0) && (wcol < 40);
  const int spc = colok ? (2 * wcol) : 0;
  const int r0 = fr0 * 5;

  const int fo = tid % 20;
  const int tr = tid / 20;
  const int to = to0 + tr;
  const bool active = (tr < 12) && (to < 500);
  const int trc = (tr < 12) ? tr : 0;

  float acc[32];
#pragma unroll
  for (int c = 0; c < 32; ++c) acc[c] = 0.f;

  __syncthreads();  // sp ready

  // fill macro body (channel ci -> buffer bf)
#define L0FILL(CIDX, BF)                                                      \
  if (filler) {                                                               \
    const float* wk = w0 + (CIDX) * 9;                                        \
    const float wv0 = wk[0], wv1 = wk[1], wv2 = wk[2], wv3 = wk[3];           \
    const float wv4 = wk[4], wv5 = wk[5], wv6 = wk[6], wv7 = wk[7];           \
    const float wv8 = wk[8];                                                  \
    const float sc = aff0[CIDX], sh = aff0[32 + (CIDX)];                      \
    int sb0 = (2 * r0) * SPS + spc;                                           \
    float t0 = sp[sb0], t1 = sp[sb0 + 1], t2 = sp[sb0 + 2];                   \
    _Pragma("unroll")                                                         \
    for (int k = 0; k < 5; ++k) {                                             \
      int r = r0 + k;                                                         \
      int mr = (2 * r + 1) * SPS + spc;                                       \
      float m0 = sp[mr], m1 = sp[mr + 1], m2 = sp[mr + 2];                    \
      float b0 = sp[mr + SPS], b1 = sp[mr + SPS + 1], b2 = sp[mr + SPS + 2];  \
      float a = t0 * wv0;                                                     \
      a = fmaf(t1, wv1, a); a = fmaf(t2, wv2, a);                             \
      a = fmaf(m0, wv3, a); a = fmaf(m1, wv4, a); a = fmaf(m2, wv5, a);       \
      a = fmaf(b0, wv6, a); a = fmaf(b1, wv7, a); a = fmaf(b2, wv8, a);       \
      int h0 = l0r0 + r;                                                      \
      bool ok = colok && h0 >= 0 && h0 < 1000;                                \
      float vv = ok ? fmaxf(fmaf(a, sc, sh), 0.f) : 0.f;                      \
      l0t[BF][r * LTS + fc] = vv;                                             \
      t0 = b0; t1 = b1; t2 = b2;                                              \
    }                                                                         \
  }

  L0FILL(0, 0)
  __syncthreads();

  for (int ci = 0; ci < 32; ++ci) {
    int cur = ci & 1;
    if (ci + 1 < 32) { L0FILL(ci + 1, cur ^ 1) }
    float xv[9];
    int base = 2 * trc * LTS + 2 * fo;
#pragma unroll
    for (int t = 0; t < 9; ++t) xv[t] = l0t[cur][base + (t / 3) * LTS + (t % 3)];
    const float* wp = w1 + ci * 9;
#pragma unroll
    for (int c = 0; c < 32; ++c) {
      const float* wc = wp + (size_t)c * 32 * 9;
#pragma unroll
      for (int t = 0; t < 9; ++t) acc[c] = fmaf(xv[t], wc[t], acc[c]);
    }
    __syncthreads();
  }
#undef L0FILL

  if (active) {
#pragma unroll
    for (int c = 0; c < 32; ++c)
      y[(((size_t)b * 32 + c) * 500 + to) * 20 + fo] = acc[c];
  }
}

// -------------------- generic conv (L2, L3, L4) ----------------------------
// Pure conv, prev-layer affine+relu folded on load, double-buffered tile.
template <int CI, int COG, int WO, int ROWS, int WI, int HI, int HO>
__global__ __launch_bounds__(256) void conv_kernel(
    const float* __restrict__ x, const float* __restrict__ w,
    const float* __restrict__ aff, float* __restrict__ y, int CO) {
  constexpr int TW = WI + 2;
  constexpr int TS = (TW & 1) ? TW : TW + 1;
  constexpr int TH = 2 * ROWS + 1;
  constexpr int TN = TH * TW;
  constexpr int F = (TN + 255) / 256;
  __shared__ float tile[2][TH * TS];

  const int tid = threadIdx.x;
  const int fo = tid % WO;
  const int tr = tid / WO;
  const int to0 = blockIdx.x * ROWS;
  const int to = to0 + tr;
  const int co0 = blockIdx.y * COG;
  const int b = blockIdx.z;
  const bool active = (tr < ROWS) && (to < HO);
  const int trc = (tr < ROWS) ? tr : 0;

  int fa[F], fof[F];
  bool fv[F], fw[F];
#pragma unroll
  for (int j = 0; j < F; ++j) {
    int i = tid + j * 256;
    int r = i / TW, c = i % TW;
    int gih = 2 * to0 - 1 + r;
    int giw = c - 1;
    bool inb = (i < TN);
    bool v = inb && gih >= 0 && gih < HI && giw >= 0 && giw < WI;
    fw[j] = inb;
    fv[j] = v;
    fof[j] = v ? (gih * WI + giw) : 0;
    fa[j] = inb ? (r * TS + c) : 0;
  }

  float acc[COG];
#pragma unroll
  for (int c = 0; c < COG; ++c) acc[c] = 0.f;

  const float* xb = x + (size_t)b * CI * HI * WI;

  {
    const float sc = aff[0], sh = aff[CI];
#pragma unroll
    for (int j = 0; j < F; ++j) {
      if (fw[j]) {
        float v = xb[fof[j]];
        v = fv[j] ? fmaxf(fmaf(v, sc, sh), 0.f) : 0.f;
        tile[0][fa[j]] = v;
      }
    }
  }
  __syncthreads();

  for (int ci = 0; ci < CI; ++ci) {
    int cur = ci & 1;
    if (ci + 1 < CI) {
      const float* xc = xb + (size_t)(ci + 1) * HI * WI;
      const float sc = aff[ci + 1], sh = aff[CI + ci + 1];
#pragma unroll
      for (int j = 0; j < F; ++j) {
        if (fw[j]) {
          float v = xc[fof[j]];
          v = fv[j] ? fmaxf(fmaf(v, sc, sh), 0.f) : 0.f;
          tile[cur ^ 1][fa[j]] = v;
        }
      }
    }
    float xv[9];
    int base = 2 * trc * TS + 2 * fo;
#pragma unroll
    for (int t = 0; t < 9; ++t) xv[t] = tile[cur][base + (t / 3) * TS + (t % 3)];
    const float* wp = w + ((size_t)co0 * CI + ci) * 9;
#pragma unroll
    for (int c = 0; c < COG; ++c) {
      const float* wc = wp + (size_t)c * CI * 9;
#pragma unroll
      for (int t = 0; t < 9; ++t) acc[c] = fmaf(xv[t], wc[t], acc[c]);
    }
    __syncthreads();
  }

  if (active) {
#pragma unroll
    for (int c = 0; c < COG; ++c)
      y[(((size_t)b * CO + co0 + c) * HO + to) * WO + fo] = acc[c];
  }
}

// -------------------- L5 (ci-split partials) -------------------------------
// grid (1, 4, 64): blockIdx.y = ci-chunk of 32. 256 threads = 64 pos x 4 cog.
__global__ __launch_bounds__(256) void conv5_kernel(
    const float* __restrict__ x, const float* __restrict__ w5,
    const float* __restrict__ aff, float* __restrict__ part5) {
  constexpr int TS = 5, TH = 65, TN = TH * TS;  // 325
  __shared__ float tile[2][TN];
  const int tid = threadIdx.x;
  const int p = tid & 63;
  const int to = p >> 1, fo = p & 1;
  const int cog = tid >> 6;
  const int co0 = cog * 32;
  const int ci0 = blockIdx.y * 32;
  const int b = blockIdx.z;

  int fa[2], fof[2];
  bool fv[2], fw[2];
#pragma unroll
  for (int j = 0; j < 2; ++j) {
    int i = tid + j * 256;
    int r = i / TS, c = i % TS;
    int gih = r - 1, giw = c - 1;
    bool inb = (i < TN);
    bool v = inb && gih >= 0 && gih < 63 && giw >= 0 && giw < 3;
    fw[j] = inb; fv[j] = v;
    fof[j] = v ? (gih * 3 + giw) : 0;
    fa[j] = inb ? i : 0;
  }

  float acc[32];
#pragma unroll
  for (int c = 0; c < 32; ++c) acc[c] = 0.f;

  const float* xb = x + (size_t)b * 128 * 189;

  {
    const float sc = aff[ci0], sh = aff[128 + ci0];
    const float* xc = xb + (size_t)ci0 * 189;
#pragma unroll
    for (int j = 0; j < 2; ++j) {
      if (fw[j]) {
        float v = xc[fof[j]];
        v = fv[j] ? fmaxf(fmaf(v, sc, sh), 0.f) : 0.f;
        tile[0][fa[j]] = v;
      }
    }
  }
  __syncthreads();

  for (int cc = 0; cc < 32; ++cc) {
    int cur = cc & 1;
    int ci = ci0 + cc;
    if (cc + 1 < 32) {
      const float* xc = xb + (size_t)(ci + 1) * 189;
      const float sc = aff[ci + 1], sh = aff[128 + ci + 1];
#pragma unroll
      for (int j = 0; j < 2; ++j) {
        if (fw[j]) {
          float v = xc[fof[j]];
          v = fv[j] ? fmaxf(fmaf(v, sc, sh), 0.f) : 0.f;
          tile[cur ^ 1][fa[j]] = v;
        }
      }
    }
    float xv[9];
#pragma unroll
    for (int t = 0; t < 9; ++t)
      xv[t] = tile[cur][(2 * to + t / 3) * TS + 2 * fo + (t % 3)];
    const float* wp = w5 + ((size_t)co0 * 128 + ci) * 9;
#pragma unroll
    for (int c = 0; c < 32; ++c) {
      const float* wc = wp + (size_t)c * 128 * 9;
#pragma unroll
      for (int t = 0; t < 9; ++t) acc[c] = fmaf(xv[t], wc[t], acc[c]);
    }
    __syncthreads();
  }

#pragma unroll
  for (int c = 0; c < 32; ++c)
    part5[(((size_t)blockIdx.y * 64 + b) * 128 + co0 + c) * 64 + p] = acc[c];
}

__global__ __launch_bounds__(256) void reduce4_kernel(const float* __restrict__ p,
                                                      float* __restrict__ y) {
  int i = blockIdx.x * 256 + threadIdx.x;
  if (i < 524288)
    y[i] = p[i] + p[i + 524288] + p[i + 2 * 524288] + p[i + 3 * 524288];
}

// -------------------- read-back BN stats (L1..L5) --------------------------
__global__ __launch_bounds__(256) void stats_kernel(const float* __restrict__ x,
                                                    float* __restrict__ part,
                                                    int C, int HW) {
  int c = blockIdx.x, b = blockIdx.y, tid = threadIdx.x;
  const float* xb = x + ((size_t)b * C + c) * HW;
  float s = 0.f, q = 0.f;
  for (int i = tid; i < HW; i += 256) {
    float v = xb[i];
    s += v;
    q = fmaf(v, v, q);
  }
#pragma unroll
  for (int m = 32; m >= 1; m >>= 1) {
    s += __shfl_xor(s, m, 64);
    q += __shfl_xor(q, m, 64);
  }
  if ((tid & 63) == 0) {
    int w = tid >> 6;
    part[(size_t)c * 256 + b * 4 + w] = s;
    part[(size_t)(C + c) * 256 + b * 4 + w] = q;
  }
}

__global__ __launch_bounds__(256) void bn_finalize(
    const float* __restrict__ part, const float* __restrict__ g,
    const float* __restrict__ bb, float* __restrict__ aff, int CO, int P,
    double invN) {
  __shared__ double s1[256];
  __shared__ double s2[256];
  int c = blockIdx.x, tid = threadIdx.x;
  double a = 0, q = 0;
  for (int i = tid; i < P; i += 256) {
    a += (double)part[(size_t)c * P + i];
    q += (double)part[(size_t)(CO + c) * P + i];
  }
  s1[tid] = a;
  s2[tid] = q;
  __syncthreads();
  for (int s = 128; s > 0; s >>= 1) {
    if (tid < s) { s1[tid] += s1[tid + s]; s2[tid] += s2[tid + s]; }
    __syncthreads();
  }
  if (tid == 0) {
    double mean = s1[0] * invN;
    double var = s2[0] * invN - mean * mean;
    float scale = g[c] * (float)(1.0 / sqrt(var + 1e-5));
    aff[c] = scale;
    aff[CO + c] = bb[c] - (float)mean * scale;
  }
}

__global__ __launch_bounds__(256) void hs_kernel(const float* __restrict__ raw,
                                                 const float* __restrict__ aff5,
                                                 float* __restrict__ hs) {
  int i = blockIdx.x * 256 + threadIdx.x;  // < 524288
  if (i >= 524288) return;
  int b = i >> 13;
  int j = i & 8191;
  int t = j >> 8;
  int d = j & 255;
  int c = d >> 1;
  int f = d & 1;
  float sc = aff5[c], sh = aff5[128 + c];
  float v = raw[(((size_t)b * 128 + c) * 32 + t) * 2 + f];
  hs[i] = fmaxf(fmaf(v, sc, sh), 0.f);
}

__global__ __launch_bounds__(256) void xw_kernel(const float* __restrict__ hs,
                                                 const float* __restrict__ w_ihT,
                                                 const float* __restrict__ bih,
                                                 float* __restrict__ xw) {
  __shared__ float sh[8 * 256];
  int tid = threadIdx.x;
  int bt0 = blockIdx.x * 8;
  for (int i = tid; i < 8 * 256; i += 256) sh[i] = hs[(size_t)bt0 * 256 + i];
  __syncthreads();
  float acc[3][8];
#pragma unroll
  for (int g = 0; g < 3; ++g)
#pragma unroll
    for (int r = 0; r < 8; ++r) acc[g][r] = 0.f;
  for (int k = 0; k < 256; ++k) {
    float w0 = w_ihT[k * 768 + tid];
    float w1 = w_ihT[k * 768 + 256 + tid];
    float w2 = w_ihT[k * 768 + 512 + tid];
#pragma unroll
    for (int r = 0; r < 8; ++r) {
      float hv = sh[r * 256 + k];
      acc[0][r] = fmaf(hv, w0, acc[0][r]);
      acc[1][r] = fmaf(hv, w1, acc[1][r]);
      acc[2][r] = fmaf(hv, w2, acc[2][r]);
    }
  }
  float b0 = bih[tid], b1 = bih[256 + tid], b2 = bih[512 + tid];
  for (int r = 0; r < 8; ++r) {
    size_t base = (size_t)(bt0 + r) * 768;
    xw[base + tid] = acc[0][r] + b0;
    xw[base + 256 + tid] = acc[1][r] + b1;
    xw[base + 512 + tid] = acc[2][r] + b2;
  }
}

__global__ __launch_bounds__(768) void gru_kernel(const float* __restrict__ xw,
                                                  const float* __restrict__ w_hhT,
                                                  const float* __restrict__ bhh,
                                                  float* __restrict__ zout) {
  __shared__ __align__(16) float h[256];
  __shared__ float gh[768];
  int b = blockIdx.x, j = threadIdx.x;
  if (j < 256) h[j] = 0.f;
  __syncthreads();
  float bh = bhh[j];
  for (int t = 0; t < 32; ++t) {
    float acc = 0.f;
    const float4* h4 = (const float4*)h;
#pragma unroll 8
    for (int k4 = 0; k4 < 64; ++k4) {
      float4 hv = h4[k4];
      const float* wr = w_hhT + (4 * k4) * 768 + j;
      acc = fmaf(hv.x, wr[0], acc);
      acc = fmaf(hv.y, wr[768], acc);
      acc = fmaf(hv.z, wr[1536], acc);
      acc = fmaf(hv.w, wr[2304], acc);
    }
    gh[j] = acc + bh;
    __syncthreads();
    float hnew = 0.f;
    if (j < 256) {
      const float* xt = xw + ((size_t)b * 32 + t) * 768;
      float ir = xt[j], iz = xt[256 + j], inn = xt[512 + j];
      float r = 1.f / (1.f + expf(-(ir + gh[j])));
      float zz = 1.f / (1.f + expf(-(iz + gh[256 + j])));
      float n = tanhf(fmaf(r, gh[512 + j], inn));
      hnew = (1.f - zz) * n + zz * h[j];
    }
    __syncthreads();
    if (j < 256) h[j] = hnew;
    __syncthreads();
  }
  if (j < 256) zout[(size_t)b * 256 + j] = h[j];
}

template <int FIRST, int LAST>
__global__ __launch_bounds__(256) void vq_stage(
    const float* __restrict__ rin, const float* __restrict__ ET,
    const float* __restrict__ sE, const float* __restrict__ E,
    float* __restrict__ zq1, float* __restrict__ zq2, float* __restrict__ rout,
    float* __restrict__ msep, float* __restrict__ i1out,
    const float* __restrict__ z0, float* __restrict__ zqsum) {
  __shared__ float rz[256];
  __shared__ float rs[256];
  __shared__ int ri[256];
  __shared__ int bidx;
  int b = blockIdx.x, tid = threadIdx.x;
  rz[tid] = rin[(size_t)b * 256 + tid];
  __syncthreads();
  float a0 = 0.f, a1 = 0.f, a2 = 0.f, a3 = 0.f;
  for (int k = 0; k < 256; ++k) {
    float zk = rz[k];
    const float* row = ET + (size_t)k * 1024 + tid;
    a0 = fmaf(zk, row[0], a0);
    a1 = fmaf(zk, row[256], a1);
    a2 = fmaf(zk, row[512], a2);
    a3 = fmaf(zk, row[768], a3);
  }
  float s0 = sE[tid] - 2.f * a0;
  float s1 = sE[256 + tid] - 2.f * a1;
  float s2 = sE[512 + tid] - 2.f * a2;
  float s3 = sE[768 + tid] - 2.f * a3;
  float bs = s0;
  int bi = tid;
  if (s1 < bs) { bs = s1; bi = 256 + tid; }
  if (s2 < bs) { bs = s2; bi = 512 + tid; }
  if (s3 < bs) { bs = s3; bi = 768 + tid; }
  rs[tid] = bs;
  ri[tid] = bi;
  __syncthreads();
  for (int s = 128; s > 0; s >>= 1) {
    if (tid < s) {
      float os = rs[tid + s];
      int oi = ri[tid + s];
      if (os < rs[tid] || (os == rs[tid] && oi < ri[tid])) { rs[tid] = os; ri[tid] = oi; }
    }
    __syncthreads();
  }
  if (tid == 0) {
    bidx = ri[0];
    if (FIRST) i1out[b] = (float)ri[0];
  }
  __syncthreads();
  int idx = bidx;
  float zq = E[(size_t)idx * 256 + tid];
  float rv = rz[tid];
  float d = zq - rv;
  float rn = rv - zq;
  zq1[(size_t)b * 768 + tid] = zq;
  zq2[(size_t)b * 256 + tid] = zq;
  rout[(size_t)b * 256 + tid] = rn;
  if (LAST) zqsum[(size_t)b * 256 + tid] = z0[(size_t)b * 256 + tid] - rn;
  rs[tid] = d * d;
  __syncthreads();
  for (int s = 128; s > 0; s >>= 1) {
    if (tid < s) rs[tid] += rs[tid + s];
    __syncthreads();
  }
  if (tid == 0) msep[b] = rs[0];
}

__global__ void loss_kernel(const float* __restrict__ msep, float* __restrict__ out) {
  if (threadIdx.x == 0 && blockIdx.x == 0) {
    float s = 0.f;
    for (int i = 0; i < 192; ++i) s += msep[i];
    out[0] = 1.25f * s / 16384.0f;
  }
}

extern "C" void kernel_launch(void* const* d_in, const int* in_sizes, int n_in,
                              void* d_out, int out_size, void* d_ws, size_t ws_size,
                              hipStream_t stream) {
  const float* speech = (const float*)d_in[0];
  const float* cw[6];
  const float* gg[6];
  const float* bbp[6];
  for (int i = 0; i < 6; ++i) {
    cw[i] = (const float*)d_in[1 + 3 * i];
    gg[i] = (const float*)d_in[2 + 3 * i];
    bbp[i] = (const float*)d_in[3 + 3 * i];
  }
  const float* w_ih = (const float*)d_in[19];
  const float* w_hh = (const float*)d_in[20];
  const float* bih = (const float*)d_in[21];
  const float* bhh = (const float*)d_in[22];
  const float* cb[3] = {(const float*)d_in[23], (const float*)d_in[24], (const float*)d_in[25]};
  float* out = (float*)d_out;
  float* ws_f = (float*)d_ws;
  (void)in_sizes; (void)n_in; (void)out_size;

  size_t off = 0;
  float* act1 = ws_f + off; off += 20480000ull;  // L1 raw; later L5 partials
  float* act2 = ws_f + off; off += 10240000ull;  // L2 raw; later L4 raw
  float* act3 = ws_f + off; off += 2560000ull;   // L3 raw; later L5 raw
  float* part = ws_f + off; off += 700000ull;
  float* affs = ws_f + off; off += 1536ull;
  float* w_ihT = ws_f + off; off += 196608ull;
  float* w_hhT = ws_f + off; off += 196608ull;
  float* hs = ws_f + off; off += 524288ull;
  float* xw = ws_f + off; off += 1572864ull;
  float* zb = ws_f + off; off += 16384ull;
  float* rA = ws_f + off; off += 16384ull;
  float* rB = ws_f + off; off += 16384ull;
  float* ET0 = ws_f + off; off += 262144ull;
  float* ET1 = ws_f + off; off += 262144ull;
  float* ET2 = ws_f + off; off += 262144ull;
  float* sEp = ws_f + off; off += 3072ull;
  float* msep = ws_f + off; off += 192ull;

  if (ws_size < off * sizeof(float)) return;  // diagnostic guard

  float* part5 = act1;  // L1 raw dead by the time conv5 runs
  float* act4 = act2;   // L2 raw dead after L3+stats
  float* act5 = act3;   // L3 raw dead after L4+stats

  const size_t OFF_LOSS = 49152;
  const size_t OFF_I1 = 49153;
  const size_t OFF_CB1 = 49217;
  const size_t OFF_CB2 = 65601;
  const size_t OFF_CB3 = 81985;
  const size_t OFF_CBSUM = 98369;

  transpose_kernel<<<256, 256, 0, stream>>>(w_ih, w_ihT, 768, 256);
  transpose_kernel<<<256, 256, 0, stream>>>(w_hh, w_hhT, 768, 256);
  transpose_kernel<<<256, 256, 0, stream>>>(cb[0], ET0, 1024, 256);
  transpose_kernel<<<256, 256, 0, stream>>>(cb[1], ET1, 1024, 256);
  transpose_kernel<<<256, 256, 0, stream>>>(cb[2], ET2, 1024, 256);
  se_kernel<<<4, 256, 0, stream>>>(ET0, sEp);
  se_kernel<<<4, 256, 0, stream>>>(ET1, sEp + 1024);
  se_kernel<<<4, 256, 0, stream>>>(ET2, sEp + 2048);

  // L0: stats only
  conv0_stats_kernel<<<dim3(42, 1, 64), 256, 0, stream>>>(speech, cw[0], part);
  bn_finalize<<<32, 256, 0, stream>>>(part, gg[0], bbp[0], affs + 0, 32, 10752,
                                      1.0 / 2560000.0);
  // L1 fused
  conv1_fused_kernel<<<dim3(42, 1, 64), 256, 0, stream>>>(speech, cw[0], affs + 0,
                                                          cw[1], act1);
  stats_kernel<<<dim3(32, 64), 256, 0, stream>>>(act1, part, 32, 10000);
  bn_finalize<<<32, 256, 0, stream>>>(part, gg[1], bbp[1], affs + 256, 32, 256,
                                      1.0 / 640000.0);
  // L2
  conv_kernel<32, 32, 10, 25, 20, 500, 250>
      <<<dim3(10, 2, 64), 256, 0, stream>>>(act1, cw[2], affs + 256, act2, 64);
  stats_kernel<<<dim3(64, 64), 256, 0, stream>>>(act2, part, 64, 2500);
  bn_finalize<<<64, 256, 0, stream>>>(part, gg[2], bbp[2], affs + 512, 64, 256,
                                      1.0 / 160000.0);
  // L3
  conv_kernel<64, 16, 5, 42, 10, 250, 125>
      <<<dim3(3, 4, 64), 256, 0, stream>>>(act2, cw[3], affs + 512, act3, 64);
  stats_kernel<<<dim3(64, 64), 256, 0, stream>>>(act3, part, 64, 625);
  bn_finalize<<<64, 256, 0, stream>>>(part, gg[3], bbp[3], affs + 768, 64, 256,
                                      1.0 / 40000.0);
  // L4
  conv_kernel<64, 16, 3, 63, 5, 125, 63>
      <<<dim3(1, 8, 64), 256, 0, stream>>>(act3, cw[4], affs + 768, act4, 128);
  stats_kernel<<<dim3(128, 64), 256, 0, stream>>>(act4, part, 128, 189);
  bn_finalize<<<128, 256, 0, stream>>>(part, gg[4], bbp[4], affs + 1024, 128, 256,
                                       1.0 / 12096.0);
  // L5 (ci-split partials into part5=act1, then reduce into act5=act3)
  conv5_kernel<<<dim3(1, 4, 64), 256, 0, stream>>>(act4, cw[5], affs + 1024, part5);
  reduce4_kernel<<<2048, 256, 0, stream>>>(part5, act5);
  stats_kernel<<<dim3(128, 64), 256, 0, stream>>>(act5, part, 128, 64);
  bn_finalize<<<128, 256, 0, stream>>>(part, gg[5], bbp[5], affs + 1280, 128, 256,
                                       1.0 / 4096.0);

  hs_kernel<<<2048, 256, 0, stream>>>(act5, affs + 1280, hs);
  xw_kernel<<<256, 256, 0, stream>>>(hs, w_ihT, bih, xw);
  gru_kernel<<<64, 768, 0, stream>>>(xw, w_hhT, bhh, zb);

  vq_stage<1, 0><<<64, 256, 0, stream>>>(zb, ET0, sEp, cb[0], out + 0, out + OFF_CB1,
                                         rA, msep + 0, out + OFF_I1, nullptr, nullptr);
  vq_stage<0, 0><<<64, 256, 0, stream>>>(rA, ET1, sEp + 1024, cb[1], out + 256,
                                         out + OFF_CB2, rB, msep + 64, nullptr, nullptr,
                                         nullptr);
  vq_stage<0, 1><<<64, 256, 0, stream>>>(rB, ET2, sEp + 2048, cb[2], out + 512,
                                         out + OFF_CB3, rA, msep + 128, nullptr, zb,
                                         out + OFF_CBSUM);
  loss_kernel<<<1, 64, 0, stream>>>(msep, out + OFF_LOSS);
}

// Round 4
// 1182.471 us; speedup vs baseline: 1.9484x; 1.0430x over previous
//
#include <hip/hip_runtime.h>
#include <math.h>

// ---------------------------------------------------------------------------
// ResidualVQ forward: 6x(conv3x3 s2 + BN + ReLU) -> GRU(32 steps) -> 3x VQ
// All fp32. L0 never materialized. All conv LDS tiles use parity-split
// planes (even/odd input columns) so stride-2 patch reads are conflict-free.
// ---------------------------------------------------------------------------

// -------------------- prep: weight transposes + codebook sE ----------------
__global__ __launch_bounds__(256) void prep_kernel(
    const float* __restrict__ w_ih, const float* __restrict__ w_hh,
    const float* __restrict__ cb0, const float* __restrict__ cb1,
    const float* __restrict__ cb2, float* __restrict__ w_ihT,
    float* __restrict__ w_hhT, float* __restrict__ ET, float* __restrict__ sE) {
  int tid = threadIdx.x;
  int y = blockIdx.y;
  if (y < 5) {
    const float* in;
    float* outp;
    int R, C;
    if (y == 0) { in = w_ih; outp = w_ihT; R = 768; C = 256; }
    else if (y == 1) { in = w_hh; outp = w_hhT; R = 768; C = 256; }
    else {
      in = (y == 2 ? cb0 : (y == 3 ? cb1 : cb2));
      outp = ET + (size_t)(y - 2) * 262144;
      R = 1024; C = 256;
    }
    int n = R * C;
    for (int t = blockIdx.x * 256 + tid; t < n; t += 64 * 256) {
      int i = t / C, j = t % C;
      outp[(size_t)j * R + i] = in[t];
    }
  } else {
    int wid = tid >> 6, lane = tid & 63;
    for (int c = blockIdx.x * 4 + wid; c < 3072; c += 64 * 4) {
      const float* E = (c < 1024 ? cb0 : (c < 2048 ? cb1 : cb2));
      int cc = c & 1023;
      float4 v4 = ((const float4*)(E + (size_t)cc * 256))[lane];
      float ssum = v4.x * v4.x + v4.y * v4.y + v4.z * v4.z + v4.w * v4.w;
#pragma unroll
      for (int m = 32; m >= 1; m >>= 1) ssum += __shfl_xor(ssum, m, 64);
      if (lane == 0) sE[c] = ssum;
    }
  }
}

// -------------------- L0 stats (conv output never stored) ------------------
__global__ __launch_bounds__(256) void conv0_stats_kernel(
    const float* __restrict__ speech, const float* __restrict__ w0,
    float* __restrict__ part) {
  constexpr int SPR = 41, SPH = 49;
  __shared__ float spE[SPH * SPR];
  __shared__ float spO[SPH * SPR];
  const int tid = threadIdx.x;
  const int bx = blockIdx.x;
  const int b = blockIdx.z;
  const int to0 = bx * 24;
  const int sr0 = 2 * to0 - 1;
  const float* sb = speech + (size_t)b * 160000;
  for (int i = tid; i < SPH * 81; i += 256) {
    int r = i / 81, c = i % 81;
    int gr = sr0 + r, gc = c - 1;
    float v = (gr >= 0 && gr < 2000 && gc >= 0 && gc < 80) ? sb[gr * 80 + gc] : 0.f;
    float* pl = (c & 1) ? spO : spE;
    pl[r * SPR + (c >> 1)] = v;
  }
  __syncthreads();

  const int fo = tid % 40;
  const int trr = tid / 40;  // 0..6 (6 -> idle)
  const bool rowok = (trr < 6);
  const int r0 = rowok ? trr * 4 : 0;

  float xv4[4][9];
  {
    int e0 = (2 * r0) * SPR + fo;
    float p0 = spE[e0], p1 = spO[e0], p2 = spE[e0 + 1];
#pragma unroll
    for (int k = 0; k < 4; ++k) {
      int mr = (2 * (r0 + k) + 1) * SPR + fo;
      int br = mr + SPR;
      xv4[k][0] = p0; xv4[k][1] = p1; xv4[k][2] = p2;
      xv4[k][3] = spE[mr]; xv4[k][4] = spO[mr]; xv4[k][5] = spE[mr + 1];
      xv4[k][6] = spE[br]; xv4[k][7] = spO[br]; xv4[k][8] = spE[br + 1];
      p0 = xv4[k][6]; p1 = xv4[k][7]; p2 = xv4[k][8];
    }
  }
  bool val[4];
#pragma unroll
  for (int k = 0; k < 4; ++k) val[k] = rowok && (to0 + r0 + k < 1000);

  float s[32], q[32];
#pragma unroll
  for (int c = 0; c < 32; ++c) { s[c] = 0.f; q[c] = 0.f; }
#pragma unroll
  for (int c = 0; c < 32; ++c) {
    const float* wk = w0 + c * 9;
    float w0v = wk[0], w1v = wk[1], w2v = wk[2], w3v = wk[3], w4v = wk[4];
    float w5v = wk[5], w6v = wk[6], w7v = wk[7], w8v = wk[8];
#pragma unroll
    for (int k = 0; k < 4; ++k) {
      float a = xv4[k][0] * w0v;
      a = fmaf(xv4[k][1], w1v, a); a = fmaf(xv4[k][2], w2v, a);
      a = fmaf(xv4[k][3], w3v, a); a = fmaf(xv4[k][4], w4v, a);
      a = fmaf(xv4[k][5], w5v, a); a = fmaf(xv4[k][6], w6v, a);
      a = fmaf(xv4[k][7], w7v, a); a = fmaf(xv4[k][8], w8v, a);
      if (val[k]) { s[c] += a; q[c] = fmaf(a, a, q[c]); }
    }
  }
  const int wid = tid >> 6;
  const int lane = tid & 63;
  const int pidx = ((b * 42 + bx) << 2) | wid;
#pragma unroll
  for (int c = 0; c < 32; ++c) {
    float ss = s[c], qq = q[c];
#pragma unroll
    for (int m = 32; m >= 1; m >>= 1) {
      ss += __shfl_xor(ss, m, 64);
      qq += __shfl_xor(qq, m, 64);
    }
    if (lane == 0) {
      part[(size_t)c * 10752 + pidx] = ss;
      part[(size_t)(32 + c) * 10752 + pidx] = qq;
    }
  }
}

// -------------------- L1 fused (recompute normalized L0) -------------------
__global__ __launch_bounds__(256) void conv1_fused_kernel(
    const float* __restrict__ speech, const float* __restrict__ w0,
    const float* __restrict__ aff0, const float* __restrict__ w1,
    float* __restrict__ y) {
  constexpr int SPR = 41, SPH = 51;
  constexpr int LPS = 21, LTH = 25, LPL = LTH * LPS;
  __shared__ float spE[SPH * SPR];
  __shared__ float spO[SPH * SPR];
  __shared__ float l0t[2][2 * LPL];  // [buf][plane*LPL + r*LPS + idx]
  const int tid = threadIdx.x;
  const int bx = blockIdx.x;
  const int b = blockIdx.z;
  const int to0 = bx * 12;
  const int l0r0 = 2 * to0 - 1;
  const int sr0 = 4 * to0 - 3;
  const float* sb = speech + (size_t)b * 160000;
  for (int i = tid; i < SPH * 81; i += 256) {
    int r = i / 81, c = i % 81;
    int gr = sr0 + r, gc = c - 1;
    float v = (gr >= 0 && gr < 2000 && gc >= 0 && gc < 80) ? sb[gr * 80 + gc] : 0.f;
    float* pl = (c & 1) ? spO : spE;
    pl[r * SPR + (c >> 1)] = v;
  }

  const int fc = tid % 42;
  const int fr0 = tid / 42;
  const bool filler = (tid < 210);
  const int wcol = fc - 1;
  const bool colok = (wcol >= 0) && (wcol < 40);
  const int wc = colok ? wcol : 0;
  const int r0 = fr0 * 5;
  const int lplane = (fc & 1) * LPL;
  const int lidx = fc >> 1;

  const int fo = tid % 20;
  const int tr = tid / 20;
  const int to = to0 + tr;
  const bool active = (tr < 12) && (to < 500);
  const int trc = (tr < 12) ? tr : 0;

  float acc[32];
#pragma unroll
  for (int c = 0; c < 32; ++c) acc[c] = 0.f;

  __syncthreads();  // sp ready

#define L0FILL(CIDX, BF)                                                      \
  if (filler) {                                                               \
    const float* wk = w0 + (CIDX) * 9;                                        \
    const float wv0 = wk[0], wv1 = wk[1], wv2 = wk[2], wv3 = wk[3];           \
    const float wv4 = wk[4], wv5 = wk[5], wv6 = wk[6], wv7 = wk[7];           \
    const float wv8 = wk[8];                                                  \
    const float sc = aff0[CIDX], sh = aff0[32 + (CIDX)];                      \
    int e0 = (2 * r0) * SPR + wc;                                             \
    float t0 = spE[e0], t1 = spO[e0], t2 = spE[e0 + 1];                       \
    _Pragma("unroll")                                                         \
    for (int k = 0; k < 5; ++k) {                                             \
      int r = r0 + k;                                                         \
      int mr = (2 * r + 1) * SPR + wc;                                        \
      int br = mr + SPR;                                                      \
      float m0 = spE[mr], m1 = spO[mr], m2 = spE[mr + 1];                     \
      float b0 = spE[br], b1 = spO[br], b2 = spE[br + 1];                     \
      float a = t0 * wv0;                                                     \
      a = fmaf(t1, wv1, a); a = fmaf(t2, wv2, a);                             \
      a = fmaf(m0, wv3, a); a = fmaf(m1, wv4, a); a = fmaf(m2, wv5, a);       \
      a = fmaf(b0, wv6, a); a = fmaf(b1, wv7, a); a = fmaf(b2, wv8, a);       \
      int h0 = l0r0 + r;                                                      \
      bool ok = colok && h0 >= 0 && h0 < 1000;                                \
      float vv = ok ? fmaxf(fmaf(a, sc, sh), 0.f) : 0.f;                      \
      l0t[BF][lplane + r * LPS + lidx] = vv;                                  \
      t0 = b0; t1 = b1; t2 = b2;                                              \
    }                                                                         \
  }

  L0FILL(0, 0)
  __syncthreads();

  for (int ci = 0; ci < 32; ++ci) {
    int cur = ci & 1;
    if (ci + 1 < 32) { L0FILL(ci + 1, cur ^ 1) }
    float xv[9];
    const int rb = 2 * trc;
#pragma unroll
    for (int t = 0; t < 9; ++t) {
      int dr = t / 3, m = t % 3;
      xv[t] = l0t[cur][(m == 1 ? LPL : 0) + (rb + dr) * LPS + fo + (m == 2 ? 1 : 0)];
    }
    const float* wp = w1 + ci * 9;
#pragma unroll
    for (int c = 0; c < 32; ++c) {
      const float* wcp = wp + (size_t)c * 32 * 9;
#pragma unroll
      for (int t = 0; t < 9; ++t) acc[c] = fmaf(xv[t], wcp[t], acc[c]);
    }
    __syncthreads();
  }
#undef L0FILL

  if (active) {
#pragma unroll
    for (int c = 0; c < 32; ++c)
      y[(((size_t)b * 32 + c) * 500 + to) * 20 + fo] = acc[c];
  }
}

// -------------------- generic conv (L2, L3, L4), parity planes -------------
template <int CI, int COG, int WO, int ROWS, int WI, int HI, int HO>
__global__ __launch_bounds__(256) void conv_kernel(
    const float* __restrict__ x, const float* __restrict__ w,
    const float* __restrict__ aff, float* __restrict__ y, int CO) {
  constexpr int TW = WI + 2;
  constexpr int PE = (TW + 1) / 2;
  constexpr int PS = PE | 1;
  constexpr int TH = 2 * ROWS + 1;
  constexpr int PL = TH * PS;
  constexpr int TN = TH * TW;
  constexpr int F = (TN + 255) / 256;
  __shared__ float tile[2][2 * PL];

  const int tid = threadIdx.x;
  const int fo = tid % WO;
  const int tr = tid / WO;
  const int to0 = blockIdx.x * ROWS;
  const int to = to0 + tr;
  const int co0 = blockIdx.y * COG;
  const int b = blockIdx.z;
  const bool active = (tr < ROWS) && (to < HO);
  const int trc = (tr < ROWS) ? tr : 0;

  int fa[F], fof[F];
  bool fv[F], fw[F];
#pragma unroll
  for (int j = 0; j < F; ++j) {
    int i = tid + j * 256;
    int r = i / TW, c = i % TW;
    int gih = 2 * to0 - 1 + r;
    int giw = c - 1;
    bool inb = (i < TN);
    bool v = inb && gih >= 0 && gih < HI && giw >= 0 && giw < WI;
    fw[j] = inb;
    fv[j] = v;
    fof[j] = v ? (gih * WI + giw) : 0;
    fa[j] = inb ? ((c & 1) * PL + r * PS + (c >> 1)) : 0;
  }

  float acc[COG];
#pragma unroll
  for (int c = 0; c < COG; ++c) acc[c] = 0.f;

  const float* xb = x + (size_t)b * CI * HI * WI;

  {
    const float sc = aff[0], sh = aff[CI];
#pragma unroll
    for (int j = 0; j < F; ++j) {
      if (fw[j]) {
        float v = xb[fof[j]];
        v = fv[j] ? fmaxf(fmaf(v, sc, sh), 0.f) : 0.f;
        tile[0][fa[j]] = v;
      }
    }
  }
  __syncthreads();

  for (int ci = 0; ci < CI; ++ci) {
    int cur = ci & 1;
    if (ci + 1 < CI) {
      const float* xc = xb + (size_t)(ci + 1) * HI * WI;
      const float sc = aff[ci + 1], sh = aff[CI + ci + 1];
#pragma unroll
      for (int j = 0; j < F; ++j) {
        if (fw[j]) {
          float v = xc[fof[j]];
          v = fv[j] ? fmaxf(fmaf(v, sc, sh), 0.f) : 0.f;
          tile[cur ^ 1][fa[j]] = v;
        }
      }
    }
    float xv[9];
    const int rb = 2 * trc;
#pragma unroll
    for (int t = 0; t < 9; ++t) {
      int dr = t / 3, m = t % 3;
      xv[t] = tile[cur][(m == 1 ? PL : 0) + (rb + dr) * PS + fo + (m == 2 ? 1 : 0)];
    }
    const float* wp = w + ((size_t)co0 * CI + ci) * 9;
#pragma unroll
    for (int c = 0; c < COG; ++c) {
      const float* wc = wp + (size_t)c * CI * 9;
#pragma unroll
      for (int t = 0; t < 9; ++t) acc[c] = fmaf(xv[t], wc[t], acc[c]);
    }
    __syncthreads();
  }

  if (active) {
#pragma unroll
    for (int c = 0; c < COG; ++c)
      y[(((size_t)b * CO + co0 + c) * HO + to) * WO + fo] = acc[c];
  }
}

// -------------------- L5 (ci-split partials), parity planes ----------------
__global__ __launch_bounds__(256) void conv5_kernel(
    const float* __restrict__ x, const float* __restrict__ w5,
    const float* __restrict__ aff, float* __restrict__ part5) {
  constexpr int TW = 5, PS = 3, TH = 65, PL = TH * PS, TN = TH * TW;
  __shared__ float tile[2][2 * PL];
  const int tid = threadIdx.x;
  const int p = tid & 63;
  const int to = p >> 1, fo = p & 1;
  const int cog = tid >> 6;
  const int co0 = cog * 32;
  const int ci0 = blockIdx.y * 32;
  const int b = blockIdx.z;

  int fa[2], fof[2];
  bool fv[2], fw[2];
#pragma unroll
  for (int j = 0; j < 2; ++j) {
    int i = tid + j * 256;
    int r = i / TW, c = i % TW;
    int gih = r - 1, giw = c - 1;
    bool inb = (i < TN);
    bool v = inb && gih >= 0 && gih < 63 && giw >= 0 && giw < 3;
    fw[j] = inb;
    fv[j] = v;
    fof[j] = v ? (gih * 3 + giw) : 0;
    fa[j] = inb ? ((c & 1) * PL + r * PS + (c >> 1)) : 0;
  }

  float acc[32];
#pragma unroll
  for (int c = 0; c < 32; ++c) acc[c] = 0.f;

  const float* xb = x + (size_t)b * 128 * 189;

  {
    const float sc = aff[ci0], sh = aff[128 + ci0];
    const float* xc = xb + (size_t)ci0 * 189;
#pragma unroll
    for (int j = 0; j < 2; ++j) {
      if (fw[j]) {
        float v = xc[fof[j]];
        v = fv[j] ? fmaxf(fmaf(v, sc, sh), 0.f) : 0.f;
        tile[0][fa[j]] = v;
      }
    }
  }
  __syncthreads();

  for (int cc = 0; cc < 32; ++cc) {
    int cur = cc & 1;
    int ci = ci0 + cc;
    if (cc + 1 < 32) {
      const float* xc = xb + (size_t)(ci + 1) * 189;
      const float sc = aff[ci + 1], sh = aff[128 + ci + 1];
#pragma unroll
      for (int j = 0; j < 2; ++j) {
        if (fw[j]) {
          float v = xc[fof[j]];
          v = fv[j] ? fmaxf(fmaf(v, sc, sh), 0.f) : 0.f;
          tile[cur ^ 1][fa[j]] = v;
        }
      }
    }
    float xv[9];
#pragma unroll
    for (int t = 0; t < 9; ++t) {
      int dr = t / 3, m = t % 3;
      xv[t] = tile[cur][(m == 1 ? PL : 0) + (2 * to + dr) * PS + fo + (m == 2 ? 1 : 0)];
    }
    const float* wp = w5 + ((size_t)co0 * 128 + ci) * 9;
#pragma unroll
    for (int c = 0; c < 32; ++c) {
      const float* wc = wp + (size_t)c * 128 * 9;
#pragma unroll
      for (int t = 0; t < 9; ++t) acc[c] = fmaf(xv[t], wc[t], acc[c]);
    }
    __syncthreads();
  }

#pragma unroll
  for (int c = 0; c < 32; ++c)
    part5[(((size_t)blockIdx.y * 64 + b) * 128 + co0 + c) * 64 + p] = acc[c];
}

__global__ __launch_bounds__(256) void reduce4_kernel(const float* __restrict__ p,
                                                      float* __restrict__ y) {
  int i = blockIdx.x * 256 + threadIdx.x;
  if (i < 524288)
    y[i] = p[i] + p[i + 524288] + p[i + 2 * 524288] + p[i + 3 * 524288];
}

// -------------------- read-back BN stats (L1..L5) --------------------------
__global__ __launch_bounds__(256) void stats_kernel(const float* __restrict__ x,
                                                    float* __restrict__ part,
                                                    int C, int HW) {
  int c = blockIdx.x, b = blockIdx.y, tid = threadIdx.x;
  const float* xb = x + ((size_t)b * C + c) * HW;
  float s = 0.f, q = 0.f;
  for (int i = tid; i < HW; i += 256) {
    float v = xb[i];
    s += v;
    q = fmaf(v, v, q);
  }
#pragma unroll
  for (int m = 32; m >= 1; m >>= 1) {
    s += __shfl_xor(s, m, 64);
    q += __shfl_xor(q, m, 64);
  }
  if ((tid & 63) == 0) {
    int w = tid >> 6;
    part[(size_t)c * 256 + b * 4 + w] = s;
    part[(size_t)(C + c) * 256 + b * 4 + w] = q;
  }
}

__global__ __launch_bounds__(256) void bn_finalize(
    const float* __restrict__ part, const float* __restrict__ g,
    const float* __restrict__ bb, float* __restrict__ aff, int CO, int P,
    double invN) {
  __shared__ double s1[256];
  __shared__ double s2[256];
  int c = blockIdx.x, tid = threadIdx.x;
  double a = 0, q = 0;
  for (int i = tid; i < P; i += 256) {
    a += (double)part[(size_t)c * P + i];
    q += (double)part[(size_t)(CO + c) * P + i];
  }
  s1[tid] = a;
  s2[tid] = q;
  __syncthreads();
  for (int s = 128; s > 0; s >>= 1) {
    if (tid < s) { s1[tid] += s1[tid + s]; s2[tid] += s2[tid + s]; }
    __syncthreads();
  }
  if (tid == 0) {
    double mean = s1[0] * invN;
    double var = s2[0] * invN - mean * mean;
    float scale = g[c] * (float)(1.0 / sqrt(var + 1e-5));
    aff[c] = scale;
    aff[CO + c] = bb[c] - (float)mean * scale;
  }
}

// -------------------- xw = relu(bn(act5)) @ w_ih^T + bih -------------------
__global__ __launch_bounds__(256) void xw_kernel(const float* __restrict__ act5,
                                                 const float* __restrict__ aff5,
                                                 const float* __restrict__ w_ihT,
                                                 const float* __restrict__ bih,
                                                 float* __restrict__ xw) {
  __shared__ float sh[8 * 256];
  int tid = threadIdx.x;
  int bt0 = blockIdx.x * 8;
  int b = bt0 >> 5;
  for (int i = tid; i < 2048; i += 256) {
    int r = i >> 8, d = i & 255, c = d >> 1, f = d & 1;
    int t = (bt0 + r) & 31;
    float v = act5[(((size_t)b * 128 + c) * 32 + t) * 2 + f];
    sh[i] = fmaxf(fmaf(v, aff5[c], aff5[128 + c]), 0.f);
  }
  __syncthreads();
  float acc[3][8];
#pragma unroll
  for (int g = 0; g < 3; ++g)
#pragma unroll
    for (int r = 0; r < 8; ++r) acc[g][r] = 0.f;
  for (int k = 0; k < 256; ++k) {
    float w0 = w_ihT[k * 768 + tid];
    float w1 = w_ihT[k * 768 + 256 + tid];
    float w2 = w_ihT[k * 768 + 512 + tid];
#pragma unroll
    for (int r = 0; r < 8; ++r) {
      float hv = sh[r * 256 + k];
      acc[0][r] = fmaf(hv, w0, acc[0][r]);
      acc[1][r] = fmaf(hv, w1, acc[1][r]);
      acc[2][r] = fmaf(hv, w2, acc[2][r]);
    }
  }
  float b0 = bih[tid], b1 = bih[256 + tid], b2 = bih[512 + tid];
  for (int r = 0; r < 8; ++r) {
    size_t base = (size_t)(bt0 + r) * 768;
    xw[base + tid] = acc[0][r] + b0;
    xw[base + 256 + tid] = acc[1][r] + b1;
    xw[base + 512 + tid] = acc[2][r] + b2;
  }
}

// -------------------- GRU recurrence ---------------------------------------
__global__ __launch_bounds__(768) void gru_kernel(const float* __restrict__ xw,
                                                  const float* __restrict__ w_hhT,
                                                  const float* __restrict__ bhh,
                                                  float* __restrict__ zout) {
  __shared__ __align__(16) float h[256];
  __shared__ float gh[768];
  int b = blockIdx.x, j = threadIdx.x;
  if (j < 256) h[j] = 0.f;
  __syncthreads();
  float bh = bhh[j];
  for (int t = 0; t < 32; ++t) {
    float acc = 0.f;
    const float4* h4 = (const float4*)h;
#pragma unroll 8
    for (int k4 = 0; k4 < 64; ++k4) {
      float4 hv = h4[k4];
      const float* wr = w_hhT + (4 * k4) * 768 + j;
      acc = fmaf(hv.x, wr[0], acc);
      acc = fmaf(hv.y, wr[768], acc);
      acc = fmaf(hv.z, wr[1536], acc);
      acc = fmaf(hv.w, wr[2304], acc);
    }
    gh[j] = acc + bh;
    __syncthreads();
    if (j < 256) {
      const float* xt = xw + ((size_t)b * 32 + t) * 768;
      float ir = xt[j], iz = xt[256 + j], inn = xt[512 + j];
      float r = 1.f / (1.f + expf(-(ir + gh[j])));
      float zz = 1.f / (1.f + expf(-(iz + gh[256 + j])));
      float n = tanhf(fmaf(r, gh[512 + j], inn));
      h[j] = (1.f - zz) * n + zz * h[j];
    }
    __syncthreads();
  }
  if (j < 256) zout[(size_t)b * 256 + j] = h[j];
}

// -------------------- fused 3-stage residual VQ ----------------------------
__global__ __launch_bounds__(256) void vq_all_kernel(
    const float* __restrict__ zb, const float* __restrict__ ET,
    const float* __restrict__ sE, const float* __restrict__ cb0,
    const float* __restrict__ cb1, const float* __restrict__ cb2,
    float* __restrict__ out, float* __restrict__ msep) {
  const size_t OFF_I1 = 49153;
  const size_t OFF_CB = 49217;
  const size_t OFF_CBSUM = 98369;
  __shared__ float rz[256];
  __shared__ float rs[256];
  __shared__ int ri[256];
  int b = blockIdx.x, tid = threadIdx.x;
  float z0 = zb[(size_t)b * 256 + tid];
  rz[tid] = z0;
  float zqs = 0.f;
  for (int s = 0; s < 3; ++s) {
    __syncthreads();  // rz ready
    const float* ETs = ET + (size_t)s * 262144;
    const float* sEs = sE + s * 1024;
    const float* E = (s == 0 ? cb0 : (s == 1 ? cb1 : cb2));
    float a0 = 0.f, a1 = 0.f, a2 = 0.f, a3 = 0.f;
    for (int k = 0; k < 256; ++k) {
      float zk = rz[k];
      const float* row = ETs + (size_t)k * 1024 + tid;
      a0 = fmaf(zk, row[0], a0);
      a1 = fmaf(zk, row[256], a1);
      a2 = fmaf(zk, row[512], a2);
      a3 = fmaf(zk, row[768], a3);
    }
    float s0 = sEs[tid] - 2.f * a0;
    float s1 = sEs[256 + tid] - 2.f * a1;
    float s2 = sEs[512 + tid] - 2.f * a2;
    float s3 = sEs[768 + tid] - 2.f * a3;
    float bs = s0;
    int bi = tid;
    if (s1 < bs) { bs = s1; bi = 256 + tid; }
    if (s2 < bs) { bs = s2; bi = 512 + tid; }
    if (s3 < bs) { bs = s3; bi = 768 + tid; }
    rs[tid] = bs;
    ri[tid] = bi;
    __syncthreads();
    for (int st = 128; st > 0; st >>= 1) {
      if (tid < st) {
        float os = rs[tid + st];
        int oi = ri[tid + st];
        if (os < rs[tid] || (os == rs[tid] && oi < ri[tid])) {
          rs[tid] = os;
          ri[tid] = oi;
        }
      }
      __syncthreads();
    }
    int idx = ri[0];
    if (s == 0 && tid == 0) out[OFF_I1 + b] = (float)idx;
    float zq = E[(size_t)idx * 256 + tid];
    float rv = rz[tid];
    float d = zq - rv;
    out[(size_t)b * 768 + s * 256 + tid] = zq;
    out[OFF_CB + (size_t)s * 16384 + (size_t)b * 256 + tid] = zq;
    zqs += zq;
    rz[tid] = rv - zq;  // safe: all reads of rz for this stage are done
    rs[tid] = d * d;
    __syncthreads();
    for (int st = 128; st > 0; st >>= 1) {
      if (tid < st) rs[tid] += rs[tid + st];
      __syncthreads();
    }
    if (tid == 0) msep[s * 64 + b] = rs[0];
  }
  out[OFF_CBSUM + (size_t)b * 256 + tid] = zqs;
}

__global__ void loss_kernel(const float* __restrict__ msep, float* __restrict__ out) {
  if (threadIdx.x == 0 && blockIdx.x == 0) {
    float s = 0.f;
    for (int i = 0; i < 192; ++i) s += msep[i];
    out[0] = 1.25f * s / 16384.0f;
  }
}

extern "C" void kernel_launch(void* const* d_in, const int* in_sizes, int n_in,
                              void* d_out, int out_size, void* d_ws, size_t ws_size,
                              hipStream_t stream) {
  const float* speech = (const float*)d_in[0];
  const float* cw[6];
  const float* gg[6];
  const float* bbp[6];
  for (int i = 0; i < 6; ++i) {
    cw[i] = (const float*)d_in[1 + 3 * i];
    gg[i] = (const float*)d_in[2 + 3 * i];
    bbp[i] = (const float*)d_in[3 + 3 * i];
  }
  const float* w_ih = (const float*)d_in[19];
  const float* w_hh = (const float*)d_in[20];
  const float* bih = (const float*)d_in[21];
  const float* bhh = (const float*)d_in[22];
  const float* cb[3] = {(const float*)d_in[23], (const float*)d_in[24], (const float*)d_in[25]};
  float* out = (float*)d_out;
  float* ws_f = (float*)d_ws;
  (void)in_sizes; (void)n_in; (void)out_size;

  size_t off = 0;
  float* act1 = ws_f + off; off += 20480000ull;  // L1 raw; later L5 partials
  float* act2 = ws_f + off; off += 10240000ull;  // L2 raw; later L4 raw
  float* act3 = ws_f + off; off += 2560000ull;   // L3 raw; later L5 raw
  float* part = ws_f + off; off += 700000ull;
  float* affs = ws_f + off; off += 1536ull;
  float* w_ihT = ws_f + off; off += 196608ull;
  float* w_hhT = ws_f + off; off += 196608ull;
  float* xw = ws_f + off; off += 1572864ull;
  float* zb = ws_f + off; off += 16384ull;
  float* ET = ws_f + off; off += 786432ull;  // ET0|ET1|ET2
  float* sEp = ws_f + off; off += 3072ull;
  float* msep = ws_f + off; off += 192ull;

  if (ws_size < off * sizeof(float)) return;  // diagnostic guard

  float* part5 = act1;
  float* act4 = act2;
  float* act5 = act3;

  const size_t OFF_LOSS = 49152;

  prep_kernel<<<dim3(64, 6), 256, 0, stream>>>(w_ih, w_hh, cb[0], cb[1], cb[2],
                                               w_ihT, w_hhT, ET, sEp);

  // L0: stats only
  conv0_stats_kernel<<<dim3(42, 1, 64), 256, 0, stream>>>(speech, cw[0], part);
  bn_finalize<<<32, 256, 0, stream>>>(part, gg[0], bbp[0], affs + 0, 32, 10752,
                                      1.0 / 2560000.0);
  // L1 fused
  conv1_fused_kernel<<<dim3(42, 1, 64), 256, 0, stream>>>(speech, cw[0], affs + 0,
                                                          cw[1], act1);
  stats_kernel<<<dim3(32, 64), 256, 0, stream>>>(act1, part, 32, 10000);
  bn_finalize<<<32, 256, 0, stream>>>(part, gg[1], bbp[1], affs + 256, 32, 256,
                                      1.0 / 640000.0);
  // L2
  conv_kernel<32, 32, 10, 25, 20, 500, 250>
      <<<dim3(10, 2, 64), 256, 0, stream>>>(act1, cw[2], affs + 256, act2, 64);
  stats_kernel<<<dim3(64, 64), 256, 0, stream>>>(act2, part, 64, 2500);
  bn_finalize<<<64, 256, 0, stream>>>(part, gg[2], bbp[2], affs + 512, 64, 256,
                                      1.0 / 160000.0);
  // L3
  conv_kernel<64, 16, 5, 42, 10, 250, 125>
      <<<dim3(3, 4, 64), 256, 0, stream>>>(act2, cw[3], affs + 512, act3, 64);
  stats_kernel<<<dim3(64, 64), 256, 0, stream>>>(act3, part, 64, 625);
  bn_finalize<<<64, 256, 0, stream>>>(part, gg[3], bbp[3], affs + 768, 64, 256,
                                      1.0 / 40000.0);
  // L4
  conv_kernel<64, 16, 3, 63, 5, 125, 63>
      <<<dim3(1, 8, 64), 256, 0, stream>>>(act3, cw[4], affs + 768, act4, 128);
  stats_kernel<<<dim3(128, 64), 256, 0, stream>>>(act4, part, 128, 189);
  bn_finalize<<<128, 256, 0, stream>>>(part, gg[4], bbp[4], affs + 1024, 128, 256,
                                       1.0 / 12096.0);
  // L5
  conv5_kernel<<<dim3(1, 4, 64), 256, 0, stream>>>(act4, cw[5], affs + 1024, part5);
  reduce4_kernel<<<2048, 256, 0, stream>>>(part5, act5);
  stats_kernel<<<dim3(128, 64), 256, 0, stream>>>(act5, part, 128, 64);
  bn_finalize<<<128, 256, 0, stream>>>(part, gg[5], bbp[5], affs + 1280, 128, 256,
                                       1.0 / 4096.0);

  xw_kernel<<<256, 256, 0, stream>>>(act5, affs + 1280, w_ihT, bih, xw);
  gru_kernel<<<64, 768, 0, stream>>>(xw, w_hhT, bhh, zb);

  vq_all_kernel<<<64, 256, 0, stream>>>(zb, ET, sEp, cb[0], cb[1], cb[2], out, msep);
  loss_kernel<<<1, 64, 0, stream>>>(msep, out + OFF_LOSS);
}